// Round 20
// baseline (179.667 us; speedup 1.0000x reference)
//
#include <hip/hip_runtime.h>
#include <math.h>

// ---------------------------------------------------------------------------
// ManifoldNetSPD, fused in log-domain.
// v20 = v19 + unroll 2 on the COT=8,K=2 conv instantiations (L3/L5/L6):
// two channels' loads issue back-to-back (halves latency exposures) while
// registers (~120) stay under the (256,4) cap -> 4 waves/SIMD retained.
// COT=8,K=3 (L2) stays unroll 1 (would hit ~130 regs -> spill risk).
// ---------------------------------------------------------------------------

#define DEVFN __device__ __forceinline__

DEVFN void jrot(float A[3][3], float V[3][3], int p, int q) {
    float apq = A[p][q];
    if (fabsf(apq) < 1e-30f) return;
    float app = A[p][p], aqq = A[q][q];
    float tau = (aqq - app) / (2.0f * apq);
    float t = copysignf(1.0f, tau) / (fabsf(tau) + sqrtf(1.0f + tau * tau));
    float c = rsqrtf(1.0f + t * t);
    float s = t * c;
    int r = 3 - p - q;
    float arp = A[r][p], arq = A[r][q];
    A[p][p] = app - t * apq;
    A[q][q] = aqq + t * apq;
    A[p][q] = 0.0f; A[q][p] = 0.0f;
    A[r][p] = c * arp - s * arq; A[p][r] = A[r][p];
    A[r][q] = s * arp + c * arq; A[q][r] = A[r][q];
#pragma unroll
    for (int i = 0; i < 3; ++i) {
        float vip = V[i][p], viq = V[i][q];
        V[i][p] = c * vip - s * viq;
        V[i][q] = s * vip + c * viq;
    }
}

DEVFN void eigh3(float A[3][3], float V[3][3]) {
    V[0][0] = 1.f; V[0][1] = 0.f; V[0][2] = 0.f;
    V[1][0] = 0.f; V[1][1] = 1.f; V[1][2] = 0.f;
    V[2][0] = 0.f; V[2][1] = 0.f; V[2][2] = 1.f;
#pragma unroll
    for (int s = 0; s < 6; ++s) {
        jrot(A, V, 0, 1);
        jrot(A, V, 0, 2);
        jrot(A, V, 1, 2);
    }
}

struct WP {
    const float* src[10];
    float* dst[10];
    int Co[10];
    int n[10];
};

// blocks 0..9: wave-parallel softmax; blocks 10..: logm -> planar [6][n].
__global__ __launch_bounds__(256)
void prep_k(WP wp, const float* __restrict__ x, float* __restrict__ out, int n) {
    if (blockIdx.x < 10) {
        const int l = blockIdx.x;
        const int wv = threadIdx.x >> 6;
        const int lane = threadIdx.x & 63;
        const int Co = wp.Co[l], nn = wp.n[l];
        for (int co = wv; co < Co; co += 4) {
            const float* src = wp.src[l] + (size_t)co * nn;
            float v0 = (lane < nn) ? src[lane] : -1e30f;
            float v1 = (lane + 64 < nn) ? src[lane + 64] : -1e30f;
            float v2 = (lane + 128 < nn) ? src[lane + 128] : -1e30f;
            float mx = fmaxf(fmaxf(v0, v1), v2);
#pragma unroll
            for (int off = 32; off; off >>= 1)
                mx = fmaxf(mx, __shfl_xor(mx, off));
            float e0 = (lane < nn) ? expf(v0 - mx) : 0.f;
            float e1 = (lane + 64 < nn) ? expf(v1 - mx) : 0.f;
            float e2 = (lane + 128 < nn) ? expf(v2 - mx) : 0.f;
            float s = e0 + e1 + e2;
#pragma unroll
            for (int off = 32; off; off >>= 1)
                s += __shfl_xor(s, off);
            float inv = 1.0f / s;
            float* dst = wp.dst[l] + (size_t)co * nn;
            if (lane < nn) dst[lane] = e0 * inv;
            if (lane + 64 < nn) dst[lane + 64] = e1 * inv;
            if (lane + 128 < nn) dst[lane + 128] = e2 * inv;
        }
        return;
    }
    int i = (blockIdx.x - 10) * 256 + threadIdx.x;
    if (i >= n) return;
    const float* m = x + (size_t)i * 9;
    float a01 = 0.5f * (m[1] + m[3]);
    float a02 = 0.5f * (m[2] + m[6]);
    float a12 = 0.5f * (m[5] + m[7]);
    float A[3][3] = {{m[0], a01, a02}, {a01, m[4], a12}, {a02, a12, m[8]}};
    float V[3][3];
    eigh3(A, V);
    float d0 = logf(fmaxf(A[0][0], 1e-30f));
    float d1 = logf(fmaxf(A[1][1], 1e-30f));
    float d2 = logf(fmaxf(A[2][2], 1e-30f));
    float L00 = V[0][0]*d0*V[0][0] + V[0][1]*d1*V[0][1] + V[0][2]*d2*V[0][2];
    float L01 = V[0][0]*d0*V[1][0] + V[0][1]*d1*V[1][1] + V[0][2]*d2*V[1][2];
    float L02 = V[0][0]*d0*V[2][0] + V[0][1]*d1*V[2][1] + V[0][2]*d2*V[2][2];
    float L11 = V[1][0]*d0*V[1][0] + V[1][1]*d1*V[1][1] + V[1][2]*d2*V[1][2];
    float L12 = V[1][0]*d0*V[2][0] + V[1][1]*d1*V[2][1] + V[1][2]*d2*V[2][2];
    float L22 = V[2][0]*d0*V[2][0] + V[2][1]*d1*V[2][1] + V[2][2]*d2*V[2][2];
    out[0 * (size_t)n + i] = L00;
    out[1 * (size_t)n + i] = L01;
    out[2 * (size_t)n + i] = L02;
    out[3 * (size_t)n + i] = L11;
    out[4 * (size_t)n + i] = L12;
    out[5 * (size_t)n + i] = L22;
}

__global__ void expm_k(const float* __restrict__ Lp, float* __restrict__ out, int n) {
    int i = blockIdx.x * blockDim.x + threadIdx.x;
    if (i >= n) return;
    float a00 = Lp[0 * (size_t)n + i];
    float a01 = Lp[1 * (size_t)n + i];
    float a02 = Lp[2 * (size_t)n + i];
    float a11 = Lp[3 * (size_t)n + i];
    float a12 = Lp[4 * (size_t)n + i];
    float a22 = Lp[5 * (size_t)n + i];
    float A[3][3] = {{a00, a01, a02}, {a01, a11, a12}, {a02, a12, a22}};
    float V[3][3];
    eigh3(A, V);
    float e0 = expf(A[0][0]);
    float e1 = expf(A[1][1]);
    float e2 = expf(A[2][2]);
    float m00 = V[0][0]*e0*V[0][0] + V[0][1]*e1*V[0][1] + V[0][2]*e2*V[0][2];
    float m01 = V[0][0]*e0*V[1][0] + V[0][1]*e1*V[1][1] + V[0][2]*e2*V[1][2];
    float m02 = V[0][0]*e0*V[2][0] + V[0][1]*e1*V[2][1] + V[0][2]*e2*V[2][2];
    float m11 = V[1][0]*e0*V[1][0] + V[1][1]*e1*V[1][1] + V[1][2]*e2*V[1][2];
    float m12 = V[1][0]*e0*V[2][0] + V[1][1]*e1*V[2][1] + V[1][2]*e2*V[2][2];
    float m22 = V[2][0]*e0*V[2][0] + V[2][1]*e1*V[2][1] + V[2][2]*e2*V[2][2];
    float* o = out + (size_t)i * 9;
    o[0] = m00; o[1] = m01; o[2] = m02;
    o[3] = m01; o[4] = m11; o[5] = m12;
    o[6] = m02; o[7] = m12; o[8] = m22;
}

// ---------------------------------------------------------------------------
// Conv v20. Input: pre-padded planar [48][CI][Hv][W4in]. Output: FULL padded
// frame [48][CO][HvOut][W4out]. Thread: 2 adjacent output rows x 4 px x
// COT channels (COT in {1,2,4,8}); loads K+1 rows per channel.
// BH = 16 * (4/NG). unroll 1 only for COT=8 & K=3; unroll 2 otherwise.
// ---------------------------------------------------------------------------
template<int CI, int CO, int K, int P2, int COT>
__global__ __launch_bounds__(256, 4)
void conv_tile(const float* __restrict__ in, float* __restrict__ out,
               const float* __restrict__ wn,
               int Hv, int W4in, int Ho, int HvOut, int W4out) {
    constexpr int NG = CO / COT;
    static_assert(4 % NG == 0, "NG must divide 4");
    constexpr int YS = 4 / NG;
    constexpr int BH = 16 * YS;
    constexpr int K2 = K * K;
    constexpr int NW = CI * K2 * CO;
    constexpr int NR = K + 1;              // input rows per channel (ROWS=2)
    constexpr int RW = 4 + K - 1;          // row width in regs

    __shared__ __align__(16) float wl[NW];

    const int tid = threadIdx.x;
    const int wv = __builtin_amdgcn_readfirstlane(tid >> 6);
    const int cog = wv % NG;
    const int ys = wv / NG;
    const int l = tid & 63;
    const int srow = ys * 16 + (l >> 3) * 2;
    const int xq = (l & 7) * 4;

    // stage softmaxed weights: wl[(ci*K2 + kh*K+kw)*CO + co]
    for (int i = tid; i < NW; i += 256) {
        int co = i % CO;
        int idx = i / CO;
        int kw = idx % K; int t = idx / K;
        int kh = t % K; int ci = t / K;
        wl[i] = wn[((co * CI + ci) * K + kh) * K + kw];
    }
    __syncthreads();

    const size_t planeIn = (size_t)Hv * W4in;
    const size_t planeOut = (size_t)HvOut * W4out;
    const int ntX = (W4out + 31) / 32;
    const int ntY = (HvOut + BH - 1) / BH;

    const int t = blockIdx.x;
    const int bx = t % ntX;
    const int rem = t / ntX;
    const int by = rem % ntY;
    const int nb = rem / ntY;
    const int gy0 = by * BH;
    const int gx0 = bx * 32;

    const int r0 = gy0 + srow;             // first output row
    // input base for (r0-P2, gx0+xq-P2); OOB stays inside ws, masked at store
    const float* base = in + (size_t)nb * CI * planeIn
                        + (long)(r0 - P2) * W4in + (gx0 + xq - P2);

    float acc[COT][2][4];
#pragma unroll
    for (int c2 = 0; c2 < COT; ++c2)
#pragma unroll
        for (int rr = 0; rr < 2; ++rr)
#pragma unroll
            for (int p = 0; p < 4; ++p) acc[c2][rr][p] = 0.f;

    auto body = [&](int cc) {
        const float* cbase = base + (size_t)cc * planeIn;
        float rv[NR][RW];
#pragma unroll
        for (int kh = 0; kh < NR; ++kh) {
            const float* rp = cbase + (long)kh * W4in;
            if constexpr ((P2 & 3) == 0) {     // 16B-aligned
                float4 a = *(const float4*)rp;
                rv[kh][0] = a.x; rv[kh][1] = a.y;
                rv[kh][2] = a.z; rv[kh][3] = a.w;
                rv[kh][4] = rp[4];
                if constexpr (K == 3) rv[kh][5] = rp[5];
            } else {                            // 8B-aligned (P2==2)
                float2 u0 = *(const float2*)rp;
                float2 u1 = *(const float2*)(rp + 2);
                rv[kh][0] = u0.x; rv[kh][1] = u0.y;
                rv[kh][2] = u1.x; rv[kh][3] = u1.y;
                rv[kh][4] = rp[4];
                if constexpr (K == 3) rv[kh][5] = rp[5];
            }
        }
        const float* wb = wl + cc * K2 * CO + cog * COT;
#pragma unroll
        for (int kh = 0; kh < K; ++kh) {
#pragma unroll
            for (int kw = 0; kw < K; ++kw) {
                if constexpr (COT == 8) {
                    const float* wp8 = wb + (kh * K + kw) * CO;
                    float4 wq0 = *(const float4*)wp8;
                    float4 wq1 = *(const float4*)(wp8 + 4);
                    float wqa[8] = {wq0.x, wq0.y, wq0.z, wq0.w,
                                    wq1.x, wq1.y, wq1.z, wq1.w};
#pragma unroll
                    for (int c2 = 0; c2 < 8; ++c2)
#pragma unroll
                        for (int rr = 0; rr < 2; ++rr)
#pragma unroll
                            for (int p = 0; p < 4; ++p)
                                acc[c2][rr][p] = fmaf(rv[kh + rr][p + kw],
                                                      wqa[c2], acc[c2][rr][p]);
                } else if constexpr (COT == 4) {
                    float4 wq = *(const float4*)(wb + (kh * K + kw) * CO);
                    float wqa[4] = {wq.x, wq.y, wq.z, wq.w};
#pragma unroll
                    for (int c2 = 0; c2 < 4; ++c2)
#pragma unroll
                        for (int rr = 0; rr < 2; ++rr)
#pragma unroll
                            for (int p = 0; p < 4; ++p)
                                acc[c2][rr][p] = fmaf(rv[kh + rr][p + kw],
                                                      wqa[c2], acc[c2][rr][p]);
                } else if constexpr (COT == 2) {
                    float2 wq = *(const float2*)(wb + (kh * K + kw) * CO);
                    float wqa[2] = {wq.x, wq.y};
#pragma unroll
                    for (int c2 = 0; c2 < 2; ++c2)
#pragma unroll
                        for (int rr = 0; rr < 2; ++rr)
#pragma unroll
                            for (int p = 0; p < 4; ++p)
                                acc[c2][rr][p] = fmaf(rv[kh + rr][p + kw],
                                                      wqa[c2], acc[c2][rr][p]);
                } else {
                    float w0 = wb[(kh * K + kw) * CO];
#pragma unroll
                    for (int rr = 0; rr < 2; ++rr)
#pragma unroll
                        for (int p = 0; p < 4; ++p)
                            acc[0][rr][p] = fmaf(rv[kh + rr][p + kw], w0,
                                                 acc[0][rr][p]);
                }
            }
        }
    };

    if constexpr (COT == 8 && K == 3) {
#pragma unroll 1
        for (int cc = 0; cc < CI; ++cc) body(cc);
    } else {
#pragma unroll 2
        for (int cc = 0; cc < CI; ++cc) body(cc);
    }

    // epilogue: 2 rows x COT float4 stores (W4out % 4 == 0 -> no straddle)
    const int cb = gx0 + xq;
    if (cb + 3 < W4out) {
#pragma unroll
        for (int rr = 0; rr < 2; ++rr) {
            const int r = r0 + rr;
            if (r < HvOut) {
                const bool rin = (r >= P2) && (r < Ho);
#pragma unroll
                for (int c2 = 0; c2 < COT; ++c2) {
                    float4 v;
                    v.x = (rin && cb + 0 >= P2 && cb + 0 < Ho) ? acc[c2][rr][0] : 0.f;
                    v.y = (rin && cb + 1 >= P2 && cb + 1 < Ho) ? acc[c2][rr][1] : 0.f;
                    v.z = (rin && cb + 2 >= P2 && cb + 2 < Ho) ? acc[c2][rr][2] : 0.f;
                    v.w = (rin && cb + 3 >= P2 && cb + 3 < Ho) ? acc[c2][rr][3] : 0.f;
                    float* ob = out
                        + ((size_t)nb * CO + cog * COT + c2) * planeOut
                        + (size_t)r * W4out + cb;
                    *(float4*)ob = v;
                }
            }
        }
    }
}

extern "C" void kernel_launch(void* const* d_in, const int* in_sizes, int n_in,
                              void* d_out, int out_size, void* d_ws, size_t ws_size,
                              hipStream_t stream) {
    const float* x = (const float*)d_in[0];
    float* out = (float*)d_out;
    float* ws = (float*)d_ws;

    static const int CiA[10] = {1, 4, 8, 16, 16, 8, 16, 16, 8, 4};
    static const int CoA[10] = {4, 8, 16, 16, 8, 16, 16, 8, 4, 1};
    static const int KA[10]  = {3, 3, 3, 2, 2, 2, 2, 3, 3, 3};

    int wnoff[11]; wnoff[0] = 0;
    for (int l = 0; l < 10; ++l)
        wnoff[l + 1] = wnoff[l] + CoA[l] * CiA[l] * KA[l] * KA[l];

    float* wn = ws;
    float* bufA = ws + 8192;
    float* bufB = bufA + 6450000;

    WP wp;
    for (int l = 0; l < 10; ++l) {
        wp.src[l] = (const float*)d_in[1 + l];
        wp.dst[l] = wn + wnoff[l];
        wp.Co[l] = CoA[l];
        wp.n[l] = CiA[l] * KA[l] * KA[l];
    }

    const int NMAT = 8 * 96 * 96;
    prep_k<<<10 + (NMAT + 255) / 256, 256, 0, stream>>>(wp, x, bufA, NMAT);

    float* cur = bufA;
    float* nxt = bufB;

#define RUN_LAYER(L_, CI_, CO_, K_, P2_, COT_, HV_, W4IN_, HO_, HVOUT_, W4OUT_) \
    {                                                                       \
        constexpr int NG_ = CO_ / COT_;                                     \
        constexpr int BH_ = 16 * (4 / NG_);                                 \
        constexpr int ntX_ = (W4OUT_ + 31) / 32;                            \
        constexpr int ntY_ = (HVOUT_ + BH_ - 1) / BH_;                      \
        conv_tile<CI_, CO_, K_, P2_, COT_>                                  \
            <<<ntX_ * ntY_ * 48, 256, 0, stream>>>(                         \
            cur, nxt, wn + wnoff[L_], HV_, W4IN_, HO_, HVOUT_, W4OUT_);     \
        { float* t = cur; cur = nxt; nxt = t; }                             \
    }

    RUN_LAYER(0,  1,  4, 3, 0, 4, 96,  96, 94, 94,  96)
    RUN_LAYER(1,  4,  8, 3, 0, 4, 94,  96, 92, 92,  92)
    RUN_LAYER(2,  8, 16, 3, 0, 8, 92,  92, 90, 90,  92)
    RUN_LAYER(3, 16, 16, 2, 0, 8, 90,  92, 89, 89,  92)
    RUN_LAYER(4, 16,  8, 2, 2, 4, 89,  92, 88, 90,  92)
    RUN_LAYER(5,  8, 16, 2, 2, 8, 90,  92, 89, 91,  92)
    RUN_LAYER(6, 16, 16, 2, 4, 8, 91,  92, 90, 94,  96)
    RUN_LAYER(7, 16,  8, 3, 4, 4, 94,  96, 92, 96,  96)
    RUN_LAYER(8,  8,  4, 3, 4, 4, 96,  96, 94, 98, 100)
    RUN_LAYER(9,  4,  1, 3, 0, 1, 98, 100, 96, 96,  96)
#undef RUN_LAYER

    expm_k<<<(NMAT + 255) / 256, 256, 0, stream>>>(cur, out, NMAT);
}

// Round 21
// 170.419 us; speedup vs baseline: 1.0543x; 1.0543x over previous
//
#include <hip/hip_runtime.h>
#include <math.h>

// ---------------------------------------------------------------------------
// ManifoldNetSPD, fused in log-domain.  (v21 == v19, the measured optimum.)
// - logm once -> 10 convs in log-domain -> expm once (expm/logm cancel;
//   identity padding == zero padding in log-domain).
// - Pre-padded planar frames [48][C][Hv][W4]: conv writes full padded frame
//   (interior = conv, border = 0), staging/bounds checks eliminated.
// - Direct global reads (L1/L2-served; staging LDS was pure overhead).
// - Weights softmaxed once, broadcast-read from LDS.
// - Thread: 2 rows x 4 px x COT channels (COT=8 on CO=16 layers).
// - unroll 2 on channel loop for COT<=4; unroll 1 for COT=8 (reg cap).
// Tuning surface mapped: ROWS=4 (v18), COT8+unroll2 (v20), dbuf (v13),
// grid/occupancy variants (v12/v14) all regress. This is the optimum.
// ---------------------------------------------------------------------------

#define DEVFN __device__ __forceinline__

DEVFN void jrot(float A[3][3], float V[3][3], int p, int q) {
    float apq = A[p][q];
    if (fabsf(apq) < 1e-30f) return;
    float app = A[p][p], aqq = A[q][q];
    float tau = (aqq - app) / (2.0f * apq);
    float t = copysignf(1.0f, tau) / (fabsf(tau) + sqrtf(1.0f + tau * tau));
    float c = rsqrtf(1.0f + t * t);
    float s = t * c;
    int r = 3 - p - q;
    float arp = A[r][p], arq = A[r][q];
    A[p][p] = app - t * apq;
    A[q][q] = aqq + t * apq;
    A[p][q] = 0.0f; A[q][p] = 0.0f;
    A[r][p] = c * arp - s * arq; A[p][r] = A[r][p];
    A[r][q] = s * arp + c * arq; A[q][r] = A[r][q];
#pragma unroll
    for (int i = 0; i < 3; ++i) {
        float vip = V[i][p], viq = V[i][q];
        V[i][p] = c * vip - s * viq;
        V[i][q] = s * vip + c * viq;
    }
}

DEVFN void eigh3(float A[3][3], float V[3][3]) {
    V[0][0] = 1.f; V[0][1] = 0.f; V[0][2] = 0.f;
    V[1][0] = 0.f; V[1][1] = 1.f; V[1][2] = 0.f;
    V[2][0] = 0.f; V[2][1] = 0.f; V[2][2] = 1.f;
#pragma unroll
    for (int s = 0; s < 6; ++s) {
        jrot(A, V, 0, 1);
        jrot(A, V, 0, 2);
        jrot(A, V, 1, 2);
    }
}

struct WP {
    const float* src[10];
    float* dst[10];
    int Co[10];
    int n[10];
};

// blocks 0..9: wave-parallel softmax; blocks 10..: logm -> planar [6][n].
__global__ __launch_bounds__(256)
void prep_k(WP wp, const float* __restrict__ x, float* __restrict__ out, int n) {
    if (blockIdx.x < 10) {
        const int l = blockIdx.x;
        const int wv = threadIdx.x >> 6;
        const int lane = threadIdx.x & 63;
        const int Co = wp.Co[l], nn = wp.n[l];
        for (int co = wv; co < Co; co += 4) {
            const float* src = wp.src[l] + (size_t)co * nn;
            float v0 = (lane < nn) ? src[lane] : -1e30f;
            float v1 = (lane + 64 < nn) ? src[lane + 64] : -1e30f;
            float v2 = (lane + 128 < nn) ? src[lane + 128] : -1e30f;
            float mx = fmaxf(fmaxf(v0, v1), v2);
#pragma unroll
            for (int off = 32; off; off >>= 1)
                mx = fmaxf(mx, __shfl_xor(mx, off));
            float e0 = (lane < nn) ? expf(v0 - mx) : 0.f;
            float e1 = (lane + 64 < nn) ? expf(v1 - mx) : 0.f;
            float e2 = (lane + 128 < nn) ? expf(v2 - mx) : 0.f;
            float s = e0 + e1 + e2;
#pragma unroll
            for (int off = 32; off; off >>= 1)
                s += __shfl_xor(s, off);
            float inv = 1.0f / s;
            float* dst = wp.dst[l] + (size_t)co * nn;
            if (lane < nn) dst[lane] = e0 * inv;
            if (lane + 64 < nn) dst[lane + 64] = e1 * inv;
            if (lane + 128 < nn) dst[lane + 128] = e2 * inv;
        }
        return;
    }
    int i = (blockIdx.x - 10) * 256 + threadIdx.x;
    if (i >= n) return;
    const float* m = x + (size_t)i * 9;
    float a01 = 0.5f * (m[1] + m[3]);
    float a02 = 0.5f * (m[2] + m[6]);
    float a12 = 0.5f * (m[5] + m[7]);
    float A[3][3] = {{m[0], a01, a02}, {a01, m[4], a12}, {a02, a12, m[8]}};
    float V[3][3];
    eigh3(A, V);
    float d0 = logf(fmaxf(A[0][0], 1e-30f));
    float d1 = logf(fmaxf(A[1][1], 1e-30f));
    float d2 = logf(fmaxf(A[2][2], 1e-30f));
    float L00 = V[0][0]*d0*V[0][0] + V[0][1]*d1*V[0][1] + V[0][2]*d2*V[0][2];
    float L01 = V[0][0]*d0*V[1][0] + V[0][1]*d1*V[1][1] + V[0][2]*d2*V[1][2];
    float L02 = V[0][0]*d0*V[2][0] + V[0][1]*d1*V[2][1] + V[0][2]*d2*V[2][2];
    float L11 = V[1][0]*d0*V[1][0] + V[1][1]*d1*V[1][1] + V[1][2]*d2*V[1][2];
    float L12 = V[1][0]*d0*V[2][0] + V[1][1]*d1*V[2][1] + V[1][2]*d2*V[2][2];
    float L22 = V[2][0]*d0*V[2][0] + V[2][1]*d1*V[2][1] + V[2][2]*d2*V[2][2];
    out[0 * (size_t)n + i] = L00;
    out[1 * (size_t)n + i] = L01;
    out[2 * (size_t)n + i] = L02;
    out[3 * (size_t)n + i] = L11;
    out[4 * (size_t)n + i] = L12;
    out[5 * (size_t)n + i] = L22;
}

__global__ void expm_k(const float* __restrict__ Lp, float* __restrict__ out, int n) {
    int i = blockIdx.x * blockDim.x + threadIdx.x;
    if (i >= n) return;
    float a00 = Lp[0 * (size_t)n + i];
    float a01 = Lp[1 * (size_t)n + i];
    float a02 = Lp[2 * (size_t)n + i];
    float a11 = Lp[3 * (size_t)n + i];
    float a12 = Lp[4 * (size_t)n + i];
    float a22 = Lp[5 * (size_t)n + i];
    float A[3][3] = {{a00, a01, a02}, {a01, a11, a12}, {a02, a12, a22}};
    float V[3][3];
    eigh3(A, V);
    float e0 = expf(A[0][0]);
    float e1 = expf(A[1][1]);
    float e2 = expf(A[2][2]);
    float m00 = V[0][0]*e0*V[0][0] + V[0][1]*e1*V[0][1] + V[0][2]*e2*V[0][2];
    float m01 = V[0][0]*e0*V[1][0] + V[0][1]*e1*V[1][1] + V[0][2]*e2*V[1][2];
    float m02 = V[0][0]*e0*V[2][0] + V[0][1]*e1*V[2][1] + V[0][2]*e2*V[2][2];
    float m11 = V[1][0]*e0*V[1][0] + V[1][1]*e1*V[1][1] + V[1][2]*e2*V[1][2];
    float m12 = V[1][0]*e0*V[2][0] + V[1][1]*e1*V[2][1] + V[1][2]*e2*V[2][2];
    float m22 = V[2][0]*e0*V[2][0] + V[2][1]*e1*V[2][1] + V[2][2]*e2*V[2][2];
    float* o = out + (size_t)i * 9;
    o[0] = m00; o[1] = m01; o[2] = m02;
    o[3] = m01; o[4] = m11; o[5] = m12;
    o[6] = m02; o[7] = m12; o[8] = m22;
}

// ---------------------------------------------------------------------------
// Conv. Input: pre-padded planar [48][CI][Hv][W4in]. Output: FULL padded
// frame [48][CO][HvOut][W4out]. Thread: 2 adjacent output rows x 4 px x
// COT channels (COT in {1,2,4,8}); loads K+1 rows per channel.
// BH = 16 * (4/NG). unroll 1 for COT=8, unroll 2 otherwise.
// ---------------------------------------------------------------------------
template<int CI, int CO, int K, int P2, int COT>
__global__ __launch_bounds__(256, 4)
void conv_tile(const float* __restrict__ in, float* __restrict__ out,
               const float* __restrict__ wn,
               int Hv, int W4in, int Ho, int HvOut, int W4out) {
    constexpr int NG = CO / COT;
    static_assert(4 % NG == 0, "NG must divide 4");
    constexpr int YS = 4 / NG;
    constexpr int BH = 16 * YS;
    constexpr int K2 = K * K;
    constexpr int NW = CI * K2 * CO;
    constexpr int NR = K + 1;              // input rows per channel (ROWS=2)
    constexpr int RW = 4 + K - 1;          // row width in regs

    __shared__ __align__(16) float wl[NW];

    const int tid = threadIdx.x;
    const int wv = __builtin_amdgcn_readfirstlane(tid >> 6);
    const int cog = wv % NG;
    const int ys = wv / NG;
    const int l = tid & 63;
    const int srow = ys * 16 + (l >> 3) * 2;
    const int xq = (l & 7) * 4;

    // stage softmaxed weights: wl[(ci*K2 + kh*K+kw)*CO + co]
    for (int i = tid; i < NW; i += 256) {
        int co = i % CO;
        int idx = i / CO;
        int kw = idx % K; int t = idx / K;
        int kh = t % K; int ci = t / K;
        wl[i] = wn[((co * CI + ci) * K + kh) * K + kw];
    }
    __syncthreads();

    const size_t planeIn = (size_t)Hv * W4in;
    const size_t planeOut = (size_t)HvOut * W4out;
    const int ntX = (W4out + 31) / 32;
    const int ntY = (HvOut + BH - 1) / BH;

    const int t = blockIdx.x;
    const int bx = t % ntX;
    const int rem = t / ntX;
    const int by = rem % ntY;
    const int nb = rem / ntY;
    const int gy0 = by * BH;
    const int gx0 = bx * 32;

    const int r0 = gy0 + srow;             // first output row
    // input base for (r0-P2, gx0+xq-P2); OOB stays inside ws, masked at store
    const float* base = in + (size_t)nb * CI * planeIn
                        + (long)(r0 - P2) * W4in + (gx0 + xq - P2);

    float acc[COT][2][4];
#pragma unroll
    for (int c2 = 0; c2 < COT; ++c2)
#pragma unroll
        for (int rr = 0; rr < 2; ++rr)
#pragma unroll
            for (int p = 0; p < 4; ++p) acc[c2][rr][p] = 0.f;

    auto body = [&](int cc) {
        const float* cbase = base + (size_t)cc * planeIn;
        float rv[NR][RW];
#pragma unroll
        for (int kh = 0; kh < NR; ++kh) {
            const float* rp = cbase + (long)kh * W4in;
            if constexpr ((P2 & 3) == 0) {     // 16B-aligned
                float4 a = *(const float4*)rp;
                rv[kh][0] = a.x; rv[kh][1] = a.y;
                rv[kh][2] = a.z; rv[kh][3] = a.w;
                rv[kh][4] = rp[4];
                if constexpr (K == 3) rv[kh][5] = rp[5];
            } else {                            // 8B-aligned (P2==2)
                float2 u0 = *(const float2*)rp;
                float2 u1 = *(const float2*)(rp + 2);
                rv[kh][0] = u0.x; rv[kh][1] = u0.y;
                rv[kh][2] = u1.x; rv[kh][3] = u1.y;
                rv[kh][4] = rp[4];
                if constexpr (K == 3) rv[kh][5] = rp[5];
            }
        }
        const float* wb = wl + cc * K2 * CO + cog * COT;
#pragma unroll
        for (int kh = 0; kh < K; ++kh) {
#pragma unroll
            for (int kw = 0; kw < K; ++kw) {
                if constexpr (COT == 8) {
                    const float* wp8 = wb + (kh * K + kw) * CO;
                    float4 wq0 = *(const float4*)wp8;
                    float4 wq1 = *(const float4*)(wp8 + 4);
                    float wqa[8] = {wq0.x, wq0.y, wq0.z, wq0.w,
                                    wq1.x, wq1.y, wq1.z, wq1.w};
#pragma unroll
                    for (int c2 = 0; c2 < 8; ++c2)
#pragma unroll
                        for (int rr = 0; rr < 2; ++rr)
#pragma unroll
                            for (int p = 0; p < 4; ++p)
                                acc[c2][rr][p] = fmaf(rv[kh + rr][p + kw],
                                                      wqa[c2], acc[c2][rr][p]);
                } else if constexpr (COT == 4) {
                    float4 wq = *(const float4*)(wb + (kh * K + kw) * CO);
                    float wqa[4] = {wq.x, wq.y, wq.z, wq.w};
#pragma unroll
                    for (int c2 = 0; c2 < 4; ++c2)
#pragma unroll
                        for (int rr = 0; rr < 2; ++rr)
#pragma unroll
                            for (int p = 0; p < 4; ++p)
                                acc[c2][rr][p] = fmaf(rv[kh + rr][p + kw],
                                                      wqa[c2], acc[c2][rr][p]);
                } else if constexpr (COT == 2) {
                    float2 wq = *(const float2*)(wb + (kh * K + kw) * CO);
                    float wqa[2] = {wq.x, wq.y};
#pragma unroll
                    for (int c2 = 0; c2 < 2; ++c2)
#pragma unroll
                        for (int rr = 0; rr < 2; ++rr)
#pragma unroll
                            for (int p = 0; p < 4; ++p)
                                acc[c2][rr][p] = fmaf(rv[kh + rr][p + kw],
                                                      wqa[c2], acc[c2][rr][p]);
                } else {
                    float w0 = wb[(kh * K + kw) * CO];
#pragma unroll
                    for (int rr = 0; rr < 2; ++rr)
#pragma unroll
                        for (int p = 0; p < 4; ++p)
                            acc[0][rr][p] = fmaf(rv[kh + rr][p + kw], w0,
                                                 acc[0][rr][p]);
                }
            }
        }
    };

    if constexpr (COT >= 8) {
#pragma unroll 1
        for (int cc = 0; cc < CI; ++cc) body(cc);
    } else {
#pragma unroll 2
        for (int cc = 0; cc < CI; ++cc) body(cc);
    }

    // epilogue: 2 rows x COT float4 stores (W4out % 4 == 0 -> no straddle)
    const int cb = gx0 + xq;
    if (cb + 3 < W4out) {
#pragma unroll
        for (int rr = 0; rr < 2; ++rr) {
            const int r = r0 + rr;
            if (r < HvOut) {
                const bool rin = (r >= P2) && (r < Ho);
#pragma unroll
                for (int c2 = 0; c2 < COT; ++c2) {
                    float4 v;
                    v.x = (rin && cb + 0 >= P2 && cb + 0 < Ho) ? acc[c2][rr][0] : 0.f;
                    v.y = (rin && cb + 1 >= P2 && cb + 1 < Ho) ? acc[c2][rr][1] : 0.f;
                    v.z = (rin && cb + 2 >= P2 && cb + 2 < Ho) ? acc[c2][rr][2] : 0.f;
                    v.w = (rin && cb + 3 >= P2 && cb + 3 < Ho) ? acc[c2][rr][3] : 0.f;
                    float* ob = out
                        + ((size_t)nb * CO + cog * COT + c2) * planeOut
                        + (size_t)r * W4out + cb;
                    *(float4*)ob = v;
                }
            }
        }
    }
}

extern "C" void kernel_launch(void* const* d_in, const int* in_sizes, int n_in,
                              void* d_out, int out_size, void* d_ws, size_t ws_size,
                              hipStream_t stream) {
    const float* x = (const float*)d_in[0];
    float* out = (float*)d_out;
    float* ws = (float*)d_ws;

    static const int CiA[10] = {1, 4, 8, 16, 16, 8, 16, 16, 8, 4};
    static const int CoA[10] = {4, 8, 16, 16, 8, 16, 16, 8, 4, 1};
    static const int KA[10]  = {3, 3, 3, 2, 2, 2, 2, 3, 3, 3};

    int wnoff[11]; wnoff[0] = 0;
    for (int l = 0; l < 10; ++l)
        wnoff[l + 1] = wnoff[l] + CoA[l] * CiA[l] * KA[l] * KA[l];

    float* wn = ws;
    float* bufA = ws + 8192;
    float* bufB = bufA + 6450000;

    WP wp;
    for (int l = 0; l < 10; ++l) {
        wp.src[l] = (const float*)d_in[1 + l];
        wp.dst[l] = wn + wnoff[l];
        wp.Co[l] = CoA[l];
        wp.n[l] = CiA[l] * KA[l] * KA[l];
    }

    const int NMAT = 8 * 96 * 96;
    prep_k<<<10 + (NMAT + 255) / 256, 256, 0, stream>>>(wp, x, bufA, NMAT);

    float* cur = bufA;
    float* nxt = bufB;

#define RUN_LAYER(L_, CI_, CO_, K_, P2_, COT_, HV_, W4IN_, HO_, HVOUT_, W4OUT_) \
    {                                                                       \
        constexpr int NG_ = CO_ / COT_;                                     \
        constexpr int BH_ = 16 * (4 / NG_);                                 \
        constexpr int ntX_ = (W4OUT_ + 31) / 32;                            \
        constexpr int ntY_ = (HVOUT_ + BH_ - 1) / BH_;                      \
        conv_tile<CI_, CO_, K_, P2_, COT_>                                  \
            <<<ntX_ * ntY_ * 48, 256, 0, stream>>>(                         \
            cur, nxt, wn + wnoff[L_], HV_, W4IN_, HO_, HVOUT_, W4OUT_);     \
        { float* t = cur; cur = nxt; nxt = t; }                             \
    }

    RUN_LAYER(0,  1,  4, 3, 0, 4, 96,  96, 94, 94,  96)
    RUN_LAYER(1,  4,  8, 3, 0, 4, 94,  96, 92, 92,  92)
    RUN_LAYER(2,  8, 16, 3, 0, 8, 92,  92, 90, 90,  92)
    RUN_LAYER(3, 16, 16, 2, 0, 8, 90,  92, 89, 89,  92)
    RUN_LAYER(4, 16,  8, 2, 2, 4, 89,  92, 88, 90,  92)
    RUN_LAYER(5,  8, 16, 2, 2, 8, 90,  92, 89, 91,  92)
    RUN_LAYER(6, 16, 16, 2, 4, 8, 91,  92, 90, 94,  96)
    RUN_LAYER(7, 16,  8, 3, 4, 4, 94,  96, 92, 96,  96)
    RUN_LAYER(8,  8,  4, 3, 4, 4, 96,  96, 94, 98, 100)
    RUN_LAYER(9,  4,  1, 3, 0, 1, 98, 100, 96, 96,  96)
#undef RUN_LAYER

    expm_k<<<(NMAT + 255) / 256, 256, 0, stream>>>(cur, out, NMAT);
}

// Round 22
// 168.020 us; speedup vs baseline: 1.0693x; 1.0143x over previous
//
#include <hip/hip_runtime.h>
#include <math.h>

// ---------------------------------------------------------------------------
// ManifoldNetSPD, fused in log-domain.
// v22 = v21 (measured optimum) + two residual-waste fixes:
//  (a) early-exit for threads whose rows are fully outside the output frame
//      (after __syncthreads; no later barriers) -> overhang waves (up to 27%
//      on BH=64 layers) stop computing/loading.
//  (b) L0: COT=2 (BH=32, 2% overhang, 432 blocks) instead of COT=4 (BH=64,
//      27% overhang, 288 blocks) -- CI=1 so per-thread reuse loss is nil.
// ---------------------------------------------------------------------------

#define DEVFN __device__ __forceinline__

DEVFN void jrot(float A[3][3], float V[3][3], int p, int q) {
    float apq = A[p][q];
    if (fabsf(apq) < 1e-30f) return;
    float app = A[p][p], aqq = A[q][q];
    float tau = (aqq - app) / (2.0f * apq);
    float t = copysignf(1.0f, tau) / (fabsf(tau) + sqrtf(1.0f + tau * tau));
    float c = rsqrtf(1.0f + t * t);
    float s = t * c;
    int r = 3 - p - q;
    float arp = A[r][p], arq = A[r][q];
    A[p][p] = app - t * apq;
    A[q][q] = aqq + t * apq;
    A[p][q] = 0.0f; A[q][p] = 0.0f;
    A[r][p] = c * arp - s * arq; A[p][r] = A[r][p];
    A[r][q] = s * arp + c * arq; A[q][r] = A[r][q];
#pragma unroll
    for (int i = 0; i < 3; ++i) {
        float vip = V[i][p], viq = V[i][q];
        V[i][p] = c * vip - s * viq;
        V[i][q] = s * vip + c * viq;
    }
}

DEVFN void eigh3(float A[3][3], float V[3][3]) {
    V[0][0] = 1.f; V[0][1] = 0.f; V[0][2] = 0.f;
    V[1][0] = 0.f; V[1][1] = 1.f; V[1][2] = 0.f;
    V[2][0] = 0.f; V[2][1] = 0.f; V[2][2] = 1.f;
#pragma unroll
    for (int s = 0; s < 6; ++s) {
        jrot(A, V, 0, 1);
        jrot(A, V, 0, 2);
        jrot(A, V, 1, 2);
    }
}

struct WP {
    const float* src[10];
    float* dst[10];
    int Co[10];
    int n[10];
};

// blocks 0..9: wave-parallel softmax; blocks 10..: logm -> planar [6][n].
__global__ __launch_bounds__(256)
void prep_k(WP wp, const float* __restrict__ x, float* __restrict__ out, int n) {
    if (blockIdx.x < 10) {
        const int l = blockIdx.x;
        const int wv = threadIdx.x >> 6;
        const int lane = threadIdx.x & 63;
        const int Co = wp.Co[l], nn = wp.n[l];
        for (int co = wv; co < Co; co += 4) {
            const float* src = wp.src[l] + (size_t)co * nn;
            float v0 = (lane < nn) ? src[lane] : -1e30f;
            float v1 = (lane + 64 < nn) ? src[lane + 64] : -1e30f;
            float v2 = (lane + 128 < nn) ? src[lane + 128] : -1e30f;
            float mx = fmaxf(fmaxf(v0, v1), v2);
#pragma unroll
            for (int off = 32; off; off >>= 1)
                mx = fmaxf(mx, __shfl_xor(mx, off));
            float e0 = (lane < nn) ? expf(v0 - mx) : 0.f;
            float e1 = (lane + 64 < nn) ? expf(v1 - mx) : 0.f;
            float e2 = (lane + 128 < nn) ? expf(v2 - mx) : 0.f;
            float s = e0 + e1 + e2;
#pragma unroll
            for (int off = 32; off; off >>= 1)
                s += __shfl_xor(s, off);
            float inv = 1.0f / s;
            float* dst = wp.dst[l] + (size_t)co * nn;
            if (lane < nn) dst[lane] = e0 * inv;
            if (lane + 64 < nn) dst[lane + 64] = e1 * inv;
            if (lane + 128 < nn) dst[lane + 128] = e2 * inv;
        }
        return;
    }
    int i = (blockIdx.x - 10) * 256 + threadIdx.x;
    if (i >= n) return;
    const float* m = x + (size_t)i * 9;
    float a01 = 0.5f * (m[1] + m[3]);
    float a02 = 0.5f * (m[2] + m[6]);
    float a12 = 0.5f * (m[5] + m[7]);
    float A[3][3] = {{m[0], a01, a02}, {a01, m[4], a12}, {a02, a12, m[8]}};
    float V[3][3];
    eigh3(A, V);
    float d0 = logf(fmaxf(A[0][0], 1e-30f));
    float d1 = logf(fmaxf(A[1][1], 1e-30f));
    float d2 = logf(fmaxf(A[2][2], 1e-30f));
    float L00 = V[0][0]*d0*V[0][0] + V[0][1]*d1*V[0][1] + V[0][2]*d2*V[0][2];
    float L01 = V[0][0]*d0*V[1][0] + V[0][1]*d1*V[1][1] + V[0][2]*d2*V[1][2];
    float L02 = V[0][0]*d0*V[2][0] + V[0][1]*d1*V[2][1] + V[0][2]*d2*V[2][2];
    float L11 = V[1][0]*d0*V[1][0] + V[1][1]*d1*V[1][1] + V[1][2]*d2*V[1][2];
    float L12 = V[1][0]*d0*V[2][0] + V[1][1]*d1*V[2][1] + V[1][2]*d2*V[2][2];
    float L22 = V[2][0]*d0*V[2][0] + V[2][1]*d1*V[2][1] + V[2][2]*d2*V[2][2];
    out[0 * (size_t)n + i] = L00;
    out[1 * (size_t)n + i] = L01;
    out[2 * (size_t)n + i] = L02;
    out[3 * (size_t)n + i] = L11;
    out[4 * (size_t)n + i] = L12;
    out[5 * (size_t)n + i] = L22;
}

__global__ void expm_k(const float* __restrict__ Lp, float* __restrict__ out, int n) {
    int i = blockIdx.x * blockDim.x + threadIdx.x;
    if (i >= n) return;
    float a00 = Lp[0 * (size_t)n + i];
    float a01 = Lp[1 * (size_t)n + i];
    float a02 = Lp[2 * (size_t)n + i];
    float a11 = Lp[3 * (size_t)n + i];
    float a12 = Lp[4 * (size_t)n + i];
    float a22 = Lp[5 * (size_t)n + i];
    float A[3][3] = {{a00, a01, a02}, {a01, a11, a12}, {a02, a12, a22}};
    float V[3][3];
    eigh3(A, V);
    float e0 = expf(A[0][0]);
    float e1 = expf(A[1][1]);
    float e2 = expf(A[2][2]);
    float m00 = V[0][0]*e0*V[0][0] + V[0][1]*e1*V[0][1] + V[0][2]*e2*V[0][2];
    float m01 = V[0][0]*e0*V[1][0] + V[0][1]*e1*V[1][1] + V[0][2]*e2*V[1][2];
    float m02 = V[0][0]*e0*V[2][0] + V[0][1]*e1*V[2][1] + V[0][2]*e2*V[2][2];
    float m11 = V[1][0]*e0*V[1][0] + V[1][1]*e1*V[1][1] + V[1][2]*e2*V[1][2];
    float m12 = V[1][0]*e0*V[2][0] + V[1][1]*e1*V[2][1] + V[1][2]*e2*V[2][2];
    float m22 = V[2][0]*e0*V[2][0] + V[2][1]*e1*V[2][1] + V[2][2]*e2*V[2][2];
    float* o = out + (size_t)i * 9;
    o[0] = m00; o[1] = m01; o[2] = m02;
    o[3] = m01; o[4] = m11; o[5] = m12;
    o[6] = m02; o[7] = m12; o[8] = m22;
}

// ---------------------------------------------------------------------------
// Conv. Input: pre-padded planar [48][CI][Hv][W4in]. Output: FULL padded
// frame [48][CO][HvOut][W4out]. Thread: 2 adjacent output rows x 4 px x
// COT channels (COT in {1,2,4,8}); loads K+1 rows per channel.
// BH = 16 * (4/NG). unroll 1 for COT=8, unroll 2 otherwise.
// Early-exit for threads whose rows are entirely outside the frame.
// ---------------------------------------------------------------------------
template<int CI, int CO, int K, int P2, int COT>
__global__ __launch_bounds__(256, 4)
void conv_tile(const float* __restrict__ in, float* __restrict__ out,
               const float* __restrict__ wn,
               int Hv, int W4in, int Ho, int HvOut, int W4out) {
    constexpr int NG = CO / COT;
    static_assert(4 % NG == 0, "NG must divide 4");
    constexpr int YS = 4 / NG;
    constexpr int BH = 16 * YS;
    constexpr int K2 = K * K;
    constexpr int NW = CI * K2 * CO;
    constexpr int NR = K + 1;              // input rows per channel (ROWS=2)
    constexpr int RW = 4 + K - 1;          // row width in regs

    __shared__ __align__(16) float wl[NW];

    const int tid = threadIdx.x;
    const int wv = __builtin_amdgcn_readfirstlane(tid >> 6);
    const int cog = wv % NG;
    const int ys = wv / NG;
    const int l = tid & 63;
    const int srow = ys * 16 + (l >> 3) * 2;
    const int xq = (l & 7) * 4;

    // stage softmaxed weights: wl[(ci*K2 + kh*K+kw)*CO + co]
    for (int i = tid; i < NW; i += 256) {
        int co = i % CO;
        int idx = i / CO;
        int kw = idx % K; int t = idx / K;
        int kh = t % K; int ci = t / K;
        wl[i] = wn[((co * CI + ci) * K + kh) * K + kw];
    }
    __syncthreads();

    const size_t planeIn = (size_t)Hv * W4in;
    const size_t planeOut = (size_t)HvOut * W4out;
    const int ntX = (W4out + 31) / 32;
    const int ntY = (HvOut + BH - 1) / BH;

    const int t = blockIdx.x;
    const int bx = t % ntX;
    const int rem = t / ntX;
    const int by = rem % ntY;
    const int nb = rem / ntY;
    const int gy0 = by * BH;
    const int gx0 = bx * 32;

    const int r0 = gy0 + srow;             // first output row
    if (r0 >= HvOut) return;               // fully-OOB rows: no barriers follow

    // input base for (r0-P2, gx0+xq-P2); OOB stays inside ws, masked at store
    const float* base = in + (size_t)nb * CI * planeIn
                        + (long)(r0 - P2) * W4in + (gx0 + xq - P2);

    float acc[COT][2][4];
#pragma unroll
    for (int c2 = 0; c2 < COT; ++c2)
#pragma unroll
        for (int rr = 0; rr < 2; ++rr)
#pragma unroll
            for (int p = 0; p < 4; ++p) acc[c2][rr][p] = 0.f;

    auto body = [&](int cc) {
        const float* cbase = base + (size_t)cc * planeIn;
        float rv[NR][RW];
#pragma unroll
        for (int kh = 0; kh < NR; ++kh) {
            const float* rp = cbase + (long)kh * W4in;
            if constexpr ((P2 & 3) == 0) {     // 16B-aligned
                float4 a = *(const float4*)rp;
                rv[kh][0] = a.x; rv[kh][1] = a.y;
                rv[kh][2] = a.z; rv[kh][3] = a.w;
                rv[kh][4] = rp[4];
                if constexpr (K == 3) rv[kh][5] = rp[5];
            } else {                            // 8B-aligned (P2==2)
                float2 u0 = *(const float2*)rp;
                float2 u1 = *(const float2*)(rp + 2);
                rv[kh][0] = u0.x; rv[kh][1] = u0.y;
                rv[kh][2] = u1.x; rv[kh][3] = u1.y;
                rv[kh][4] = rp[4];
                if constexpr (K == 3) rv[kh][5] = rp[5];
            }
        }
        const float* wb = wl + cc * K2 * CO + cog * COT;
#pragma unroll
        for (int kh = 0; kh < K; ++kh) {
#pragma unroll
            for (int kw = 0; kw < K; ++kw) {
                if constexpr (COT == 8) {
                    const float* wp8 = wb + (kh * K + kw) * CO;
                    float4 wq0 = *(const float4*)wp8;
                    float4 wq1 = *(const float4*)(wp8 + 4);
                    float wqa[8] = {wq0.x, wq0.y, wq0.z, wq0.w,
                                    wq1.x, wq1.y, wq1.z, wq1.w};
#pragma unroll
                    for (int c2 = 0; c2 < 8; ++c2)
#pragma unroll
                        for (int rr = 0; rr < 2; ++rr)
#pragma unroll
                            for (int p = 0; p < 4; ++p)
                                acc[c2][rr][p] = fmaf(rv[kh + rr][p + kw],
                                                      wqa[c2], acc[c2][rr][p]);
                } else if constexpr (COT == 4) {
                    float4 wq = *(const float4*)(wb + (kh * K + kw) * CO);
                    float wqa[4] = {wq.x, wq.y, wq.z, wq.w};
#pragma unroll
                    for (int c2 = 0; c2 < 4; ++c2)
#pragma unroll
                        for (int rr = 0; rr < 2; ++rr)
#pragma unroll
                            for (int p = 0; p < 4; ++p)
                                acc[c2][rr][p] = fmaf(rv[kh + rr][p + kw],
                                                      wqa[c2], acc[c2][rr][p]);
                } else if constexpr (COT == 2) {
                    float2 wq = *(const float2*)(wb + (kh * K + kw) * CO);
                    float wqa[2] = {wq.x, wq.y};
#pragma unroll
                    for (int c2 = 0; c2 < 2; ++c2)
#pragma unroll
                        for (int rr = 0; rr < 2; ++rr)
#pragma unroll
                            for (int p = 0; p < 4; ++p)
                                acc[c2][rr][p] = fmaf(rv[kh + rr][p + kw],
                                                      wqa[c2], acc[c2][rr][p]);
                } else {
                    float w0 = wb[(kh * K + kw) * CO];
#pragma unroll
                    for (int rr = 0; rr < 2; ++rr)
#pragma unroll
                        for (int p = 0; p < 4; ++p)
                            acc[0][rr][p] = fmaf(rv[kh + rr][p + kw], w0,
                                                 acc[0][rr][p]);
                }
            }
        }
    };

    if constexpr (COT >= 8) {
#pragma unroll 1
        for (int cc = 0; cc < CI; ++cc) body(cc);
    } else {
#pragma unroll 2
        for (int cc = 0; cc < CI; ++cc) body(cc);
    }

    // epilogue: 2 rows x COT float4 stores (W4out % 4 == 0 -> no straddle)
    const int cb = gx0 + xq;
    if (cb + 3 < W4out) {
#pragma unroll
        for (int rr = 0; rr < 2; ++rr) {
            const int r = r0 + rr;
            if (r < HvOut) {
                const bool rin = (r >= P2) && (r < Ho);
#pragma unroll
                for (int c2 = 0; c2 < COT; ++c2) {
                    float4 v;
                    v.x = (rin && cb + 0 >= P2 && cb + 0 < Ho) ? acc[c2][rr][0] : 0.f;
                    v.y = (rin && cb + 1 >= P2 && cb + 1 < Ho) ? acc[c2][rr][1] : 0.f;
                    v.z = (rin && cb + 2 >= P2 && cb + 2 < Ho) ? acc[c2][rr][2] : 0.f;
                    v.w = (rin && cb + 3 >= P2 && cb + 3 < Ho) ? acc[c2][rr][3] : 0.f;
                    float* ob = out
                        + ((size_t)nb * CO + cog * COT + c2) * planeOut
                        + (size_t)r * W4out + cb;
                    *(float4*)ob = v;
                }
            }
        }
    }
}

extern "C" void kernel_launch(void* const* d_in, const int* in_sizes, int n_in,
                              void* d_out, int out_size, void* d_ws, size_t ws_size,
                              hipStream_t stream) {
    const float* x = (const float*)d_in[0];
    float* out = (float*)d_out;
    float* ws = (float*)d_ws;

    static const int CiA[10] = {1, 4, 8, 16, 16, 8, 16, 16, 8, 4};
    static const int CoA[10] = {4, 8, 16, 16, 8, 16, 16, 8, 4, 1};
    static const int KA[10]  = {3, 3, 3, 2, 2, 2, 2, 3, 3, 3};

    int wnoff[11]; wnoff[0] = 0;
    for (int l = 0; l < 10; ++l)
        wnoff[l + 1] = wnoff[l] + CoA[l] * CiA[l] * KA[l] * KA[l];

    float* wn = ws;
    float* bufA = ws + 8192;
    float* bufB = bufA + 6450000;

    WP wp;
    for (int l = 0; l < 10; ++l) {
        wp.src[l] = (const float*)d_in[1 + l];
        wp.dst[l] = wn + wnoff[l];
        wp.Co[l] = CoA[l];
        wp.n[l] = CiA[l] * KA[l] * KA[l];
    }

    const int NMAT = 8 * 96 * 96;
    prep_k<<<10 + (NMAT + 255) / 256, 256, 0, stream>>>(wp, x, bufA, NMAT);

    float* cur = bufA;
    float* nxt = bufB;

#define RUN_LAYER(L_, CI_, CO_, K_, P2_, COT_, HV_, W4IN_, HO_, HVOUT_, W4OUT_) \
    {                                                                       \
        constexpr int NG_ = CO_ / COT_;                                     \
        constexpr int BH_ = 16 * (4 / NG_);                                 \
        constexpr int ntX_ = (W4OUT_ + 31) / 32;                            \
        constexpr int ntY_ = (HVOUT_ + BH_ - 1) / BH_;                      \
        conv_tile<CI_, CO_, K_, P2_, COT_>                                  \
            <<<ntX_ * ntY_ * 48, 256, 0, stream>>>(                         \
            cur, nxt, wn + wnoff[L_], HV_, W4IN_, HO_, HVOUT_, W4OUT_);     \
        { float* t = cur; cur = nxt; nxt = t; }                             \
    }

    RUN_LAYER(0,  1,  4, 3, 0, 2, 96,  96, 94, 94,  96)
    RUN_LAYER(1,  4,  8, 3, 0, 4, 94,  96, 92, 92,  92)
    RUN_LAYER(2,  8, 16, 3, 0, 8, 92,  92, 90, 90,  92)
    RUN_LAYER(3, 16, 16, 2, 0, 8, 90,  92, 89, 89,  92)
    RUN_LAYER(4, 16,  8, 2, 2, 4, 89,  92, 88, 90,  92)
    RUN_LAYER(5,  8, 16, 2, 2, 8, 90,  92, 89, 91,  92)
    RUN_LAYER(6, 16, 16, 2, 4, 8, 91,  92, 90, 94,  96)
    RUN_LAYER(7, 16,  8, 3, 4, 4, 94,  96, 92, 96,  96)
    RUN_LAYER(8,  8,  4, 3, 4, 4, 96,  96, 94, 98, 100)
    RUN_LAYER(9,  4,  1, 3, 0, 1, 98, 100, 96, 96,  96)
#undef RUN_LAYER

    expm_k<<<(NMAT + 255) / 256, 256, 0, stream>>>(cur, out, NMAT);
}

// Round 23
// 165.027 us; speedup vs baseline: 1.0887x; 1.0181x over previous
//
#include <hip/hip_runtime.h>
#include <math.h>

// ---------------------------------------------------------------------------
// ManifoldNetSPD, fused in log-domain.
// v23 = v22 + nb-MAJOR BLOCK ORDER (XCD-consistent): nb = blockIdx % 48, so
// with round-robin block->XCD dispatch, plane-set nb always maps to XCD nb%8
// in EVERY layer. Each (comp,batch) chain (<=542 KB/layer) stays resident in
// one XCD's 4MB L2 across the whole 10-layer sequence -> inter-layer reads
// become local-L2 hits instead of cross-XCD L3 fetches.
// ---------------------------------------------------------------------------

#define DEVFN __device__ __forceinline__

DEVFN void jrot(float A[3][3], float V[3][3], int p, int q) {
    float apq = A[p][q];
    if (fabsf(apq) < 1e-30f) return;
    float app = A[p][p], aqq = A[q][q];
    float tau = (aqq - app) / (2.0f * apq);
    float t = copysignf(1.0f, tau) / (fabsf(tau) + sqrtf(1.0f + tau * tau));
    float c = rsqrtf(1.0f + t * t);
    float s = t * c;
    int r = 3 - p - q;
    float arp = A[r][p], arq = A[r][q];
    A[p][p] = app - t * apq;
    A[q][q] = aqq + t * apq;
    A[p][q] = 0.0f; A[q][p] = 0.0f;
    A[r][p] = c * arp - s * arq; A[p][r] = A[r][p];
    A[r][q] = s * arp + c * arq; A[q][r] = A[r][q];
#pragma unroll
    for (int i = 0; i < 3; ++i) {
        float vip = V[i][p], viq = V[i][q];
        V[i][p] = c * vip - s * viq;
        V[i][q] = s * vip + c * viq;
    }
}

DEVFN void eigh3(float A[3][3], float V[3][3]) {
    V[0][0] = 1.f; V[0][1] = 0.f; V[0][2] = 0.f;
    V[1][0] = 0.f; V[1][1] = 1.f; V[1][2] = 0.f;
    V[2][0] = 0.f; V[2][1] = 0.f; V[2][2] = 1.f;
#pragma unroll
    for (int s = 0; s < 6; ++s) {
        jrot(A, V, 0, 1);
        jrot(A, V, 0, 2);
        jrot(A, V, 1, 2);
    }
}

struct WP {
    const float* src[10];
    float* dst[10];
    int Co[10];
    int n[10];
};

// blocks 0..9: wave-parallel softmax; blocks 10..: logm -> planar [6][n].
__global__ __launch_bounds__(256)
void prep_k(WP wp, const float* __restrict__ x, float* __restrict__ out, int n) {
    if (blockIdx.x < 10) {
        const int l = blockIdx.x;
        const int wv = threadIdx.x >> 6;
        const int lane = threadIdx.x & 63;
        const int Co = wp.Co[l], nn = wp.n[l];
        for (int co = wv; co < Co; co += 4) {
            const float* src = wp.src[l] + (size_t)co * nn;
            float v0 = (lane < nn) ? src[lane] : -1e30f;
            float v1 = (lane + 64 < nn) ? src[lane + 64] : -1e30f;
            float v2 = (lane + 128 < nn) ? src[lane + 128] : -1e30f;
            float mx = fmaxf(fmaxf(v0, v1), v2);
#pragma unroll
            for (int off = 32; off; off >>= 1)
                mx = fmaxf(mx, __shfl_xor(mx, off));
            float e0 = (lane < nn) ? expf(v0 - mx) : 0.f;
            float e1 = (lane + 64 < nn) ? expf(v1 - mx) : 0.f;
            float e2 = (lane + 128 < nn) ? expf(v2 - mx) : 0.f;
            float s = e0 + e1 + e2;
#pragma unroll
            for (int off = 32; off; off >>= 1)
                s += __shfl_xor(s, off);
            float inv = 1.0f / s;
            float* dst = wp.dst[l] + (size_t)co * nn;
            if (lane < nn) dst[lane] = e0 * inv;
            if (lane + 64 < nn) dst[lane + 64] = e1 * inv;
            if (lane + 128 < nn) dst[lane + 128] = e2 * inv;
        }
        return;
    }
    int i = (blockIdx.x - 10) * 256 + threadIdx.x;
    if (i >= n) return;
    const float* m = x + (size_t)i * 9;
    float a01 = 0.5f * (m[1] + m[3]);
    float a02 = 0.5f * (m[2] + m[6]);
    float a12 = 0.5f * (m[5] + m[7]);
    float A[3][3] = {{m[0], a01, a02}, {a01, m[4], a12}, {a02, a12, m[8]}};
    float V[3][3];
    eigh3(A, V);
    float d0 = logf(fmaxf(A[0][0], 1e-30f));
    float d1 = logf(fmaxf(A[1][1], 1e-30f));
    float d2 = logf(fmaxf(A[2][2], 1e-30f));
    float L00 = V[0][0]*d0*V[0][0] + V[0][1]*d1*V[0][1] + V[0][2]*d2*V[0][2];
    float L01 = V[0][0]*d0*V[1][0] + V[0][1]*d1*V[1][1] + V[0][2]*d2*V[1][2];
    float L02 = V[0][0]*d0*V[2][0] + V[0][1]*d1*V[2][1] + V[0][2]*d2*V[2][2];
    float L11 = V[1][0]*d0*V[1][0] + V[1][1]*d1*V[1][1] + V[1][2]*d2*V[1][2];
    float L12 = V[1][0]*d0*V[2][0] + V[1][1]*d1*V[2][1] + V[1][2]*d2*V[2][2];
    float L22 = V[2][0]*d0*V[2][0] + V[2][1]*d1*V[2][1] + V[2][2]*d2*V[2][2];
    out[0 * (size_t)n + i] = L00;
    out[1 * (size_t)n + i] = L01;
    out[2 * (size_t)n + i] = L02;
    out[3 * (size_t)n + i] = L11;
    out[4 * (size_t)n + i] = L12;
    out[5 * (size_t)n + i] = L22;
}

__global__ void expm_k(const float* __restrict__ Lp, float* __restrict__ out, int n) {
    int i = blockIdx.x * blockDim.x + threadIdx.x;
    if (i >= n) return;
    float a00 = Lp[0 * (size_t)n + i];
    float a01 = Lp[1 * (size_t)n + i];
    float a02 = Lp[2 * (size_t)n + i];
    float a11 = Lp[3 * (size_t)n + i];
    float a12 = Lp[4 * (size_t)n + i];
    float a22 = Lp[5 * (size_t)n + i];
    float A[3][3] = {{a00, a01, a02}, {a01, a11, a12}, {a02, a12, a22}};
    float V[3][3];
    eigh3(A, V);
    float e0 = expf(A[0][0]);
    float e1 = expf(A[1][1]);
    float e2 = expf(A[2][2]);
    float m00 = V[0][0]*e0*V[0][0] + V[0][1]*e1*V[0][1] + V[0][2]*e2*V[0][2];
    float m01 = V[0][0]*e0*V[1][0] + V[0][1]*e1*V[1][1] + V[0][2]*e2*V[1][2];
    float m02 = V[0][0]*e0*V[2][0] + V[0][1]*e1*V[2][1] + V[0][2]*e2*V[2][2];
    float m11 = V[1][0]*e0*V[1][0] + V[1][1]*e1*V[1][1] + V[1][2]*e2*V[1][2];
    float m12 = V[1][0]*e0*V[2][0] + V[1][1]*e1*V[2][1] + V[1][2]*e2*V[2][2];
    float m22 = V[2][0]*e0*V[2][0] + V[2][1]*e1*V[2][1] + V[2][2]*e2*V[2][2];
    float* o = out + (size_t)i * 9;
    o[0] = m00; o[1] = m01; o[2] = m02;
    o[3] = m01; o[4] = m11; o[5] = m12;
    o[6] = m02; o[7] = m12; o[8] = m22;
}

// ---------------------------------------------------------------------------
// Conv. Input: pre-padded planar [48][CI][Hv][W4in]. Output: FULL padded
// frame [48][CO][HvOut][W4out]. Thread: 2 adjacent output rows x 4 px x
// COT channels (COT in {1,2,4,8}); loads K+1 rows per channel.
// BH = 16 * (4/NG). unroll 1 for COT=8, unroll 2 otherwise.
// Block decomposition nb-major: nb = blockIdx % 48 (XCD-consistent).
// Early-exit for threads whose rows are entirely outside the frame.
// ---------------------------------------------------------------------------
template<int CI, int CO, int K, int P2, int COT>
__global__ __launch_bounds__(256, 4)
void conv_tile(const float* __restrict__ in, float* __restrict__ out,
               const float* __restrict__ wn,
               int Hv, int W4in, int Ho, int HvOut, int W4out) {
    constexpr int NG = CO / COT;
    static_assert(4 % NG == 0, "NG must divide 4");
    constexpr int YS = 4 / NG;
    constexpr int BH = 16 * YS;
    constexpr int K2 = K * K;
    constexpr int NW = CI * K2 * CO;
    constexpr int NR = K + 1;              // input rows per channel (ROWS=2)
    constexpr int RW = 4 + K - 1;          // row width in regs

    __shared__ __align__(16) float wl[NW];

    const int tid = threadIdx.x;
    const int wv = __builtin_amdgcn_readfirstlane(tid >> 6);
    const int cog = wv % NG;
    const int ys = wv / NG;
    const int l = tid & 63;
    const int srow = ys * 16 + (l >> 3) * 2;
    const int xq = (l & 7) * 4;

    // stage softmaxed weights: wl[(ci*K2 + kh*K+kw)*CO + co]
    for (int i = tid; i < NW; i += 256) {
        int co = i % CO;
        int idx = i / CO;
        int kw = idx % K; int t = idx / K;
        int kh = t % K; int ci = t / K;
        wl[i] = wn[((co * CI + ci) * K + kh) * K + kw];
    }
    __syncthreads();

    const size_t planeIn = (size_t)Hv * W4in;
    const size_t planeOut = (size_t)HvOut * W4out;
    const int ntX = (W4out + 31) / 32;

    // nb-major decomposition: nb fastest -> block i has nb == i % 48, so with
    // round-robin block->XCD dispatch, plane-set nb maps to XCD nb%8 in every
    // layer (producer/consumer L2 locality).
    const int t = blockIdx.x;
    const int nb = t % 48;
    const int rem = t / 48;
    const int bx = rem % ntX;
    const int by = rem / ntX;
    const int gy0 = by * BH;
    const int gx0 = bx * 32;

    const int r0 = gy0 + srow;             // first output row
    if (r0 >= HvOut) return;               // fully-OOB rows: no barriers follow

    // input base for (r0-P2, gx0+xq-P2); OOB stays inside ws, masked at store
    const float* base = in + (size_t)nb * CI * planeIn
                        + (long)(r0 - P2) * W4in + (gx0 + xq - P2);

    float acc[COT][2][4];
#pragma unroll
    for (int c2 = 0; c2 < COT; ++c2)
#pragma unroll
        for (int rr = 0; rr < 2; ++rr)
#pragma unroll
            for (int p = 0; p < 4; ++p) acc[c2][rr][p] = 0.f;

    auto body = [&](int cc) {
        const float* cbase = base + (size_t)cc * planeIn;
        float rv[NR][RW];
#pragma unroll
        for (int kh = 0; kh < NR; ++kh) {
            const float* rp = cbase + (long)kh * W4in;
            if constexpr ((P2 & 3) == 0) {     // 16B-aligned
                float4 a = *(const float4*)rp;
                rv[kh][0] = a.x; rv[kh][1] = a.y;
                rv[kh][2] = a.z; rv[kh][3] = a.w;
                rv[kh][4] = rp[4];
                if constexpr (K == 3) rv[kh][5] = rp[5];
            } else {                            // 8B-aligned (P2==2)
                float2 u0 = *(const float2*)rp;
                float2 u1 = *(const float2*)(rp + 2);
                rv[kh][0] = u0.x; rv[kh][1] = u0.y;
                rv[kh][2] = u1.x; rv[kh][3] = u1.y;
                rv[kh][4] = rp[4];
                if constexpr (K == 3) rv[kh][5] = rp[5];
            }
        }
        const float* wb = wl + cc * K2 * CO + cog * COT;
#pragma unroll
        for (int kh = 0; kh < K; ++kh) {
#pragma unroll
            for (int kw = 0; kw < K; ++kw) {
                if constexpr (COT == 8) {
                    const float* wp8 = wb + (kh * K + kw) * CO;
                    float4 wq0 = *(const float4*)wp8;
                    float4 wq1 = *(const float4*)(wp8 + 4);
                    float wqa[8] = {wq0.x, wq0.y, wq0.z, wq0.w,
                                    wq1.x, wq1.y, wq1.z, wq1.w};
#pragma unroll
                    for (int c2 = 0; c2 < 8; ++c2)
#pragma unroll
                        for (int rr = 0; rr < 2; ++rr)
#pragma unroll
                            for (int p = 0; p < 4; ++p)
                                acc[c2][rr][p] = fmaf(rv[kh + rr][p + kw],
                                                      wqa[c2], acc[c2][rr][p]);
                } else if constexpr (COT == 4) {
                    float4 wq = *(const float4*)(wb + (kh * K + kw) * CO);
                    float wqa[4] = {wq.x, wq.y, wq.z, wq.w};
#pragma unroll
                    for (int c2 = 0; c2 < 4; ++c2)
#pragma unroll
                        for (int rr = 0; rr < 2; ++rr)
#pragma unroll
                            for (int p = 0; p < 4; ++p)
                                acc[c2][rr][p] = fmaf(rv[kh + rr][p + kw],
                                                      wqa[c2], acc[c2][rr][p]);
                } else if constexpr (COT == 2) {
                    float2 wq = *(const float2*)(wb + (kh * K + kw) * CO);
                    float wqa[2] = {wq.x, wq.y};
#pragma unroll
                    for (int c2 = 0; c2 < 2; ++c2)
#pragma unroll
                        for (int rr = 0; rr < 2; ++rr)
#pragma unroll
                            for (int p = 0; p < 4; ++p)
                                acc[c2][rr][p] = fmaf(rv[kh + rr][p + kw],
                                                      wqa[c2], acc[c2][rr][p]);
                } else {
                    float w0 = wb[(kh * K + kw) * CO];
#pragma unroll
                    for (int rr = 0; rr < 2; ++rr)
#pragma unroll
                        for (int p = 0; p < 4; ++p)
                            acc[0][rr][p] = fmaf(rv[kh + rr][p + kw], w0,
                                                 acc[0][rr][p]);
                }
            }
        }
    };

    if constexpr (COT >= 8) {
#pragma unroll 1
        for (int cc = 0; cc < CI; ++cc) body(cc);
    } else {
#pragma unroll 2
        for (int cc = 0; cc < CI; ++cc) body(cc);
    }

    // epilogue: 2 rows x COT float4 stores (W4out % 4 == 0 -> no straddle)
    const int cb = gx0 + xq;
    if (cb + 3 < W4out) {
#pragma unroll
        for (int rr = 0; rr < 2; ++rr) {
            const int r = r0 + rr;
            if (r < HvOut) {
                const bool rin = (r >= P2) && (r < Ho);
#pragma unroll
                for (int c2 = 0; c2 < COT; ++c2) {
                    float4 v;
                    v.x = (rin && cb + 0 >= P2 && cb + 0 < Ho) ? acc[c2][rr][0] : 0.f;
                    v.y = (rin && cb + 1 >= P2 && cb + 1 < Ho) ? acc[c2][rr][1] : 0.f;
                    v.z = (rin && cb + 2 >= P2 && cb + 2 < Ho) ? acc[c2][rr][2] : 0.f;
                    v.w = (rin && cb + 3 >= P2 && cb + 3 < Ho) ? acc[c2][rr][3] : 0.f;
                    float* ob = out
                        + ((size_t)nb * CO + cog * COT + c2) * planeOut
                        + (size_t)r * W4out + cb;
                    *(float4*)ob = v;
                }
            }
        }
    }
}

extern "C" void kernel_launch(void* const* d_in, const int* in_sizes, int n_in,
                              void* d_out, int out_size, void* d_ws, size_t ws_size,
                              hipStream_t stream) {
    const float* x = (const float*)d_in[0];
    float* out = (float*)d_out;
    float* ws = (float*)d_ws;

    static const int CiA[10] = {1, 4, 8, 16, 16, 8, 16, 16, 8, 4};
    static const int CoA[10] = {4, 8, 16, 16, 8, 16, 16, 8, 4, 1};
    static const int KA[10]  = {3, 3, 3, 2, 2, 2, 2, 3, 3, 3};

    int wnoff[11]; wnoff[0] = 0;
    for (int l = 0; l < 10; ++l)
        wnoff[l + 1] = wnoff[l] + CoA[l] * CiA[l] * KA[l] * KA[l];

    float* wn = ws;
    float* bufA = ws + 8192;
    float* bufB = bufA + 6450000;

    WP wp;
    for (int l = 0; l < 10; ++l) {
        wp.src[l] = (const float*)d_in[1 + l];
        wp.dst[l] = wn + wnoff[l];
        wp.Co[l] = CoA[l];
        wp.n[l] = CiA[l] * KA[l] * KA[l];
    }

    const int NMAT = 8 * 96 * 96;
    prep_k<<<10 + (NMAT + 255) / 256, 256, 0, stream>>>(wp, x, bufA, NMAT);

    float* cur = bufA;
    float* nxt = bufB;

#define RUN_LAYER(L_, CI_, CO_, K_, P2_, COT_, HV_, W4IN_, HO_, HVOUT_, W4OUT_) \
    {                                                                       \
        constexpr int NG_ = CO_ / COT_;                                     \
        constexpr int BH_ = 16 * (4 / NG_);                                 \
        constexpr int ntX_ = (W4OUT_ + 31) / 32;                            \
        constexpr int ntY_ = (HVOUT_ + BH_ - 1) / BH_;                      \
        conv_tile<CI_, CO_, K_, P2_, COT_>                                  \
            <<<ntX_ * ntY_ * 48, 256, 0, stream>>>(                         \
            cur, nxt, wn + wnoff[L_], HV_, W4IN_, HO_, HVOUT_, W4OUT_);     \
        { float* t = cur; cur = nxt; nxt = t; }                             \
    }

    RUN_LAYER(0,  1,  4, 3, 0, 2, 96,  96, 94, 94,  96)
    RUN_LAYER(1,  4,  8, 3, 0, 4, 94,  96, 92, 92,  92)
    RUN_LAYER(2,  8, 16, 3, 0, 8, 92,  92, 90, 90,  92)
    RUN_LAYER(3, 16, 16, 2, 0, 8, 90,  92, 89, 89,  92)
    RUN_LAYER(4, 16,  8, 2, 2, 4, 89,  92, 88, 90,  92)
    RUN_LAYER(5,  8, 16, 2, 2, 8, 90,  92, 89, 91,  92)
    RUN_LAYER(6, 16, 16, 2, 4, 8, 91,  92, 90, 94,  96)
    RUN_LAYER(7, 16,  8, 3, 4, 4, 94,  96, 92, 96,  96)
    RUN_LAYER(8,  8,  4, 3, 4, 4, 96,  96, 94, 98, 100)
    RUN_LAYER(9,  4,  1, 3, 0, 1, 98, 100, 96, 96,  96)
#undef RUN_LAYER

    expm_k<<<(NMAT + 255) / 256, 256, 0, stream>>>(cur, out, NMAT);
}